// Round 1
// baseline (166.857 us; speedup 1.0000x reference)
//
#include <hip/hip_runtime.h>

// FDLT: out[b,m,o] = sum_i psiHat[b,m,i] * E[m][i][o]
//   E[m] = cm * X_parity(m) @ D[m]^T   (X = XFc even m, XFs odd m)
// BATCH=2048, B=128 (m), N=256 (i), O=128 (o)
//
// Kernel 1: Et[m][o][i] (bf16, o-major so main-kernel B-frags are contiguous
//           along k=i) into d_ws. bf16 MFMA, fragments direct from global.
// Kernel 2: per (b-tile of 32, m): (32x256)@(256x128) GEMM, bf16 MFMA,
//           no LDS: A-frags from fp32 psiHat (cvt in-reg), B-frags from Et.

typedef __attribute__((ext_vector_type(8))) short short8;
typedef __attribute__((ext_vector_type(4))) float f32x4;

#define NBATCH 2048
#define NM 128
#define NI 256   // K dim (i / j)
#define NO 128   // output o dim

__device__ __forceinline__ unsigned short f2bf(float f) {
  // round-to-nearest-even fp32 -> bf16
  unsigned int u = __builtin_bit_cast(unsigned int, f);
  u += 0x7FFFu + ((u >> 16) & 1u);
  return (unsigned short)(u >> 16);
}

__device__ __forceinline__ short8 cvt8(float4 a, float4 b, float s) {
  short8 v;
  v[0] = (short)f2bf(s * a.x); v[1] = (short)f2bf(s * a.y);
  v[2] = (short)f2bf(s * a.z); v[3] = (short)f2bf(s * a.w);
  v[4] = (short)f2bf(s * b.x); v[5] = (short)f2bf(s * b.y);
  v[6] = (short)f2bf(s * b.z); v[7] = (short)f2bf(s * b.w);
  return v;
}

// ---------------- Kernel 1: E precompute ----------------
// grid: 256 blocks (m = bx>>1, i-half = bx&1), 256 threads = 4 waves.
// wave computes 32(i) x 128(o); K = j over 256.
// A(i,j) = cm * Xp[i][j]; B(j,o) = D[m][o][j]  (contiguous along j per lane).
// Write Et[m][o][i] bf16.
__global__ __launch_bounds__(256) void e_kernel(
    const float* __restrict__ XFc, const float* __restrict__ XFs,
    const float* __restrict__ D, const float* __restrict__ cmp,
    unsigned short* __restrict__ Et)
{
  const int m = blockIdx.x >> 1;
  const int ihalf = blockIdx.x & 1;
  const int tid = threadIdx.x;
  const int lane = tid & 63;
  const int w = tid >> 6;
  const int lr = lane & 15;   // frag row (A) / col (B)
  const int lg = lane >> 4;   // k group
  const float cm = cmp[0];
  const float* __restrict__ Xp = (m & 1) ? XFs : XFc;
  const float* __restrict__ Dm = D + (size_t)m * (NO * NI);
  const int i0 = ihalf * 128 + w * 32;

  f32x4 acc[2][8];
#pragma unroll
  for (int a = 0; a < 2; a++)
#pragma unroll
    for (int b = 0; b < 8; b++) acc[a][b] = (f32x4)0.f;

  for (int kk = 0; kk < NI; kk += 32) {
    const int kb = kk + lg * 8;
    short8 af[2];
#pragma unroll
    for (int rf = 0; rf < 2; rf++) {
      const float* ap = Xp + (size_t)(i0 + rf * 16 + lr) * NI + kb;
      float4 x0 = *(const float4*)ap;
      float4 x1 = *(const float4*)(ap + 4);
      af[rf] = cvt8(x0, x1, cm);
    }
    short8 bf[8];
#pragma unroll
    for (int cf = 0; cf < 8; cf++) {
      const float* bp = Dm + (size_t)(cf * 16 + lr) * NI + kb;
      float4 x0 = *(const float4*)bp;
      float4 x1 = *(const float4*)(bp + 4);
      bf[cf] = cvt8(x0, x1, 1.0f);
    }
#pragma unroll
    for (int rf = 0; rf < 2; rf++)
#pragma unroll
      for (int cf = 0; cf < 8; cf++)
        acc[rf][cf] = __builtin_amdgcn_mfma_f32_16x16x32_bf16(
            af[rf], bf[cf], acc[rf][cf], 0, 0, 0);
  }

  // C/D layout: col = lane&15 (= o), row = (lane>>4)*4 + reg (= i offset)
  unsigned short* Em = Et + (size_t)m * (NO * NI);
#pragma unroll
  for (int rf = 0; rf < 2; rf++)
#pragma unroll
    for (int cf = 0; cf < 8; cf++) {
      const int i = i0 + rf * 16 + lg * 4;
      const int o = cf * 16 + lr;
      ushort4 pk;
      pk.x = f2bf(acc[rf][cf][0]);
      pk.y = f2bf(acc[rf][cf][1]);
      pk.z = f2bf(acc[rf][cf][2]);
      pk.w = f2bf(acc[rf][cf][3]);
      *(ushort4*)(Em + (size_t)o * NI + i) = pk;
    }
}

// ---------------- Kernel 2: main GEMM ----------------
// grid: (2048/32, 128), 64 threads (1 wave).
// wave computes out[b0..b0+31][m][0..127]; K = i over 256, step 32.
__global__ __launch_bounds__(64) void fdlt_main(
    const float* __restrict__ psiHat,
    const unsigned short* __restrict__ Et,
    float* __restrict__ out)
{
  const int b0 = blockIdx.x * 32;
  const int m = blockIdx.y;
  const int lane = threadIdx.x;
  const int lr = lane & 15;
  const int lg = lane >> 4;

  f32x4 acc[2][8];
#pragma unroll
  for (int a = 0; a < 2; a++)
#pragma unroll
    for (int b = 0; b < 8; b++) acc[a][b] = (f32x4)0.f;

  const unsigned short* __restrict__ Em = Et + (size_t)m * (NO * NI);

  for (int kk = 0; kk < NI; kk += 32) {
    const int kb = kk + lg * 8;
    short8 af[2];
#pragma unroll
    for (int rf = 0; rf < 2; rf++) {
      // psiHat[b][m][i], row (b,m) is 256 contiguous floats
      const float* ap = psiHat + ((size_t)(b0 + rf * 16 + lr) * NM + m) * NI + kb;
      float4 x0 = *(const float4*)ap;
      float4 x1 = *(const float4*)(ap + 4);
      af[rf] = cvt8(x0, x1, 1.0f);
    }
    short8 bf[8];
#pragma unroll
    for (int cf = 0; cf < 8; cf++) {
      // Et[m][o][i]: 8 bf16 contiguous along i = 16B
      bf[cf] = *(const short8*)(Em + (size_t)(cf * 16 + lr) * NI + kb);
    }
#pragma unroll
    for (int rf = 0; rf < 2; rf++)
#pragma unroll
      for (int cf = 0; cf < 8; cf++)
        acc[rf][cf] = __builtin_amdgcn_mfma_f32_16x16x32_bf16(
            af[rf], bf[cf], acc[rf][cf], 0, 0, 0);
  }

  // out[b][m][o]; C/D: col = lane&15 (= o), row = (lane>>4)*4+reg (= b offset)
#pragma unroll
  for (int rf = 0; rf < 2; rf++)
#pragma unroll
    for (int cf = 0; cf < 8; cf++) {
      const int o = cf * 16 + lr;
#pragma unroll
      for (int r = 0; r < 4; r++) {
        const int b = b0 + rf * 16 + lg * 4 + r;
        out[((size_t)b * NM + m) * NO + o] = acc[rf][cf][r];
      }
    }
}

extern "C" void kernel_launch(void* const* d_in, const int* in_sizes, int n_in,
                              void* d_out, int out_size, void* d_ws, size_t ws_size,
                              hipStream_t stream) {
  const float* psiHat = (const float*)d_in[0];
  const float* cm     = (const float*)d_in[1];
  const float* XFc    = (const float*)d_in[2];
  const float* XFs    = (const float*)d_in[3];
  const float* D      = (const float*)d_in[4];
  float* out = (float*)d_out;
  unsigned short* Et = (unsigned short*)d_ws;  // 128*128*256*2 = 8.39 MB

  e_kernel<<<256, 256, 0, stream>>>(XFc, XFs, D, cm, Et);
  fdlt_main<<<dim3(NBATCH / 32, NM), 64, 0, stream>>>(psiHat, Et, out);
}

// Round 2
// 153.561 us; speedup vs baseline: 1.0866x; 1.0866x over previous
//
#include <hip/hip_runtime.h>

// FDLT: out[b,m,o] = sum_i psiHat[b,m,i] * E[m][i][o]
//   E[m] = cm * X_parity(m) @ D[m]^T   (X = XFc even m, XFs odd m)
// BATCH=2048, B=128 (m), N=256 (i), O=128 (o)
//
// Kernel 1: Et[m][o][i] (bf16, o-major so main-kernel B-frags are contiguous
//           along k=i) into d_ws.
// Kernel 2: 256-thread blocks (4 waves), block = 128(b) x 128(o) tile at one m;
//           each wave does 32(b) x 128(o). B-frags shared by all 4 waves -> L1.
//           No LDS. Latency hidden by ~8 blocks/CU residency.

typedef __attribute__((ext_vector_type(8))) short short8;
typedef __attribute__((ext_vector_type(4))) float f32x4;

#define NBATCH 2048
#define NM 128
#define NI 256   // K dim (i / j)
#define NO 128   // output o dim

__device__ __forceinline__ unsigned short f2bf(float f) {
  // round-to-nearest-even fp32 -> bf16
  unsigned int u = __builtin_bit_cast(unsigned int, f);
  u += 0x7FFFu + ((u >> 16) & 1u);
  return (unsigned short)(u >> 16);
}

__device__ __forceinline__ short8 cvt8(float4 a, float4 b, float s) {
  short8 v;
  v[0] = (short)f2bf(s * a.x); v[1] = (short)f2bf(s * a.y);
  v[2] = (short)f2bf(s * a.z); v[3] = (short)f2bf(s * a.w);
  v[4] = (short)f2bf(s * b.x); v[5] = (short)f2bf(s * b.y);
  v[6] = (short)f2bf(s * b.z); v[7] = (short)f2bf(s * b.w);
  return v;
}

// ---------------- Kernel 1: E precompute ----------------
// grid: 256 blocks (m = bx>>1, i-half = bx&1), 256 threads = 4 waves.
// wave computes 32(i) x 128(o); K = j over 256.
// A(i,j) = cm * Xp[i][j]; B(j,o) = D[m][o][j]  (contiguous along j per lane).
// Write Et[m][o][i] bf16.
__global__ __launch_bounds__(256) void e_kernel(
    const float* __restrict__ XFc, const float* __restrict__ XFs,
    const float* __restrict__ D, const float* __restrict__ cmp,
    unsigned short* __restrict__ Et)
{
  const int m = blockIdx.x >> 1;
  const int ihalf = blockIdx.x & 1;
  const int tid = threadIdx.x;
  const int lane = tid & 63;
  const int w = tid >> 6;
  const int lr = lane & 15;   // frag row (A) / col (B)
  const int lg = lane >> 4;   // k group
  const float cm = cmp[0];
  const float* __restrict__ Xp = (m & 1) ? XFs : XFc;
  const float* __restrict__ Dm = D + (size_t)m * (NO * NI);
  const int i0 = ihalf * 128 + w * 32;

  f32x4 acc[2][8];
#pragma unroll
  for (int a = 0; a < 2; a++)
#pragma unroll
    for (int b = 0; b < 8; b++) acc[a][b] = (f32x4)0.f;

  for (int kk = 0; kk < NI; kk += 32) {
    const int kb = kk + lg * 8;
    short8 af[2];
#pragma unroll
    for (int rf = 0; rf < 2; rf++) {
      const float* ap = Xp + (size_t)(i0 + rf * 16 + lr) * NI + kb;
      float4 x0 = *(const float4*)ap;
      float4 x1 = *(const float4*)(ap + 4);
      af[rf] = cvt8(x0, x1, cm);
    }
    short8 bf[8];
#pragma unroll
    for (int cf = 0; cf < 8; cf++) {
      const float* bp = Dm + (size_t)(cf * 16 + lr) * NI + kb;
      float4 x0 = *(const float4*)bp;
      float4 x1 = *(const float4*)(bp + 4);
      bf[cf] = cvt8(x0, x1, 1.0f);
    }
#pragma unroll
    for (int rf = 0; rf < 2; rf++)
#pragma unroll
      for (int cf = 0; cf < 8; cf++)
        acc[rf][cf] = __builtin_amdgcn_mfma_f32_16x16x32_bf16(
            af[rf], bf[cf], acc[rf][cf], 0, 0, 0);
  }

  // C/D layout: col = lane&15 (= o), row = (lane>>4)*4 + reg (= i offset)
  unsigned short* Em = Et + (size_t)m * (NO * NI);
#pragma unroll
  for (int rf = 0; rf < 2; rf++)
#pragma unroll
    for (int cf = 0; cf < 8; cf++) {
      const int i = i0 + rf * 16 + lg * 4;
      const int o = cf * 16 + lr;
      ushort4 pk;
      pk.x = f2bf(acc[rf][cf][0]);
      pk.y = f2bf(acc[rf][cf][1]);
      pk.z = f2bf(acc[rf][cf][2]);
      pk.w = f2bf(acc[rf][cf][3]);
      *(ushort4*)(Em + (size_t)o * NI + i) = pk;
    }
}

// ---------------- Kernel 2: main GEMM ----------------
// grid: (2048/128, 128), 256 threads = 4 waves.
// Block computes out[b0..b0+127][m][0..127]; wave w takes b-rows b0+w*32..+31.
// K = i over 256, step 32. All 4 waves share the same B-frags (L1 hits).
__global__ __launch_bounds__(256) void fdlt_main(
    const float* __restrict__ psiHat,
    const unsigned short* __restrict__ Et,
    float* __restrict__ out)
{
  const int m = blockIdx.y;
  const int tid = threadIdx.x;
  const int lane = tid & 63;
  const int w = tid >> 6;
  const int b0 = blockIdx.x * 128 + w * 32;
  const int lr = lane & 15;
  const int lg = lane >> 4;

  f32x4 acc[2][8];
#pragma unroll
  for (int a = 0; a < 2; a++)
#pragma unroll
    for (int b = 0; b < 8; b++) acc[a][b] = (f32x4)0.f;

  const unsigned short* __restrict__ Em = Et + (size_t)m * (NO * NI);

  for (int kk = 0; kk < NI; kk += 32) {
    const int kb = kk + lg * 8;
    short8 af[2];
#pragma unroll
    for (int rf = 0; rf < 2; rf++) {
      // psiHat[b][m][i], row (b,m) is 256 contiguous floats
      const float* ap = psiHat + ((size_t)(b0 + rf * 16 + lr) * NM + m) * NI + kb;
      float4 x0 = *(const float4*)ap;
      float4 x1 = *(const float4*)(ap + 4);
      af[rf] = cvt8(x0, x1, 1.0f);
    }
    short8 bf[8];
#pragma unroll
    for (int cf = 0; cf < 8; cf++) {
      // Et[m][o][i]: 8 bf16 contiguous along i = 16B
      bf[cf] = *(const short8*)(Em + (size_t)(cf * 16 + lr) * NI + kb);
    }
#pragma unroll
    for (int rf = 0; rf < 2; rf++)
#pragma unroll
      for (int cf = 0; cf < 8; cf++)
        acc[rf][cf] = __builtin_amdgcn_mfma_f32_16x16x32_bf16(
            af[rf], bf[cf], acc[rf][cf], 0, 0, 0);
  }

  // out[b][m][o]; C/D: col = lane&15 (= o), row = (lane>>4)*4+reg (= b offset)
#pragma unroll
  for (int rf = 0; rf < 2; rf++)
#pragma unroll
    for (int cf = 0; cf < 8; cf++) {
      const int o = cf * 16 + lr;
#pragma unroll
      for (int r = 0; r < 4; r++) {
        const int b = b0 + rf * 16 + lg * 4 + r;
        out[((size_t)b * NM + m) * NO + o] = acc[rf][cf][r];
      }
    }
}

extern "C" void kernel_launch(void* const* d_in, const int* in_sizes, int n_in,
                              void* d_out, int out_size, void* d_ws, size_t ws_size,
                              hipStream_t stream) {
  const float* psiHat = (const float*)d_in[0];
  const float* cm     = (const float*)d_in[1];
  const float* XFc    = (const float*)d_in[2];
  const float* XFs    = (const float*)d_in[3];
  const float* D      = (const float*)d_in[4];
  float* out = (float*)d_out;
  unsigned short* Et = (unsigned short*)d_ws;  // 128*128*256*2 = 8.39 MB

  e_kernel<<<256, 256, 0, stream>>>(XFc, XFs, D, cm, Et);
  fdlt_main<<<dim3(NBATCH / 128, NM), 256, 0, stream>>>(psiHat, Et, out);
}